// Round 1
// baseline (2247.273 us; speedup 1.0000x reference)
//
#include <hip/hip_runtime.h>
#include <math.h>

#define NN   40000
#define EE   640000
#define FD   128
#define HD   128
#define SUBG 400
#define CELLS 100
#define BNEPS 1e-5f

// ---------------- degree / normalization ----------------
__global__ void k_deg_init(float* deg) {
    int i = blockIdx.x * blockDim.x + threadIdx.x;
    if (i < NN) deg[i] = 1.0f;   // self-loop contributes 1
}

__global__ void k_deg_count(const int* __restrict__ dst, float* __restrict__ deg) {
    int i = blockIdx.x * blockDim.x + threadIdx.x;
    int stride = gridDim.x * blockDim.x;
    for (; i < EE; i += stride) atomicAdd(&deg[dst[i]], 1.0f);
}

__global__ void k_dis(float* deg) {
    int i = blockIdx.x * blockDim.x + threadIdx.x;
    if (i < NN) deg[i] = rsqrtf(deg[i]);   // deg >= 1 always
}

// ---------------- dense GEMM  Y[M,128] = X[M,128] @ W[128,128] ----------------
__global__ void k_gemm128(const float* __restrict__ X, const float* __restrict__ W,
                          float* __restrict__ Y, int M) {
    __shared__ float wl[FD * HD];   // 64 KB
    int t = threadIdx.x;
    for (int i = t * 4; i < FD * HD; i += 256 * 4)
        *(float4*)&wl[i] = *(const float4*)&W[i];
    __syncthreads();

    int lane = t & 63;
    int wid  = t >> 6;
    int gw = blockIdx.x * 4 + wid;
    int nw = gridDim.x * 4;
    for (int row = gw; row < M; row += nw) {
        const float* xr = X + (long)row * 128;
        float xv0 = xr[lane];
        float xv1 = xr[64 + lane];
        float2 acc = {0.f, 0.f};
#pragma unroll
        for (int k = 0; k < 64; ++k) {
            float xk = __shfl(xv0, k);
            float2 w = *(const float2*)&wl[k * 128 + 2 * lane];
            acc.x += xk * w.x; acc.y += xk * w.y;
        }
#pragma unroll
        for (int k = 0; k < 64; ++k) {
            float xk = __shfl(xv1, k);
            float2 w = *(const float2*)&wl[(64 + k) * 128 + 2 * lane];
            acc.x += xk * w.x; acc.y += xk * w.y;
        }
        *(float2*)&Y[(long)row * 128 + 2 * lane] = acc;
    }
}

// ---------------- GCN aggregation ----------------
// out[i,:] = h[i,:] * dis[i]^2 + bias  (self loop + conv bias)
__global__ void k_selfloop_bias(const float* __restrict__ Hm, const float* __restrict__ dis,
                                const float* __restrict__ bias, float* __restrict__ out) {
    int i = blockIdx.x * blockDim.x + threadIdx.x;   // float4 index
    int total = NN * HD / 4;
    int stride = gridDim.x * blockDim.x;
    for (; i < total; i += stride) {
        int row = i >> 5;           // 32 float4 per row
        int c4 = (i & 31) * 4;
        float dd = dis[row]; dd = dd * dd;
        float4 h4 = ((const float4*)Hm)[i];
        float4 b4 = *(const float4*)&bias[c4];
        float4 o;
        o.x = h4.x * dd + b4.x;
        o.y = h4.y * dd + b4.y;
        o.z = h4.z * dd + b4.z;
        o.w = h4.w * dd + b4.w;
        ((float4*)out)[i] = o;
    }
}

// one wave per edge: out[d,:] += h[s,:] * dis[s]*dis[d]
__global__ void k_scatter(const float* __restrict__ Hm, const int* __restrict__ src,
                          const int* __restrict__ dst, const float* __restrict__ dis,
                          float* __restrict__ out) {
    int lane = threadIdx.x & 63;
    int gw = (blockIdx.x * blockDim.x + threadIdx.x) >> 6;
    int nw = (gridDim.x * blockDim.x) >> 6;
    for (int e = gw; e < EE; e += nw) {
        int s = src[e], d = dst[e];
        float n = dis[s] * dis[d];
        float2 v = *(const float2*)&Hm[(long)s * 128 + 2 * lane];
        atomicAdd(&out[(long)d * 128 + 2 * lane],     v.x * n);
        atomicAdd(&out[(long)d * 128 + 2 * lane + 1], v.y * n);
    }
}

// ---------------- BatchNorm (batch stats over N rows, 128 cols) ----------------
__global__ void k_zero(float* p, int n) {
    int i = blockIdx.x * blockDim.x + threadIdx.x;
    if (i < n) p[i] = 0.f;
}

__global__ void k_bnstats(const float* __restrict__ X, float* __restrict__ stats,
                          int rowsPerBlock) {
    __shared__ float ls[256], ls2[256];
    int t = threadIdx.x;
    int col = t & 127, half = t >> 7;
    int r0 = blockIdx.x * rowsPerBlock;
    int r1 = r0 + rowsPerBlock; if (r1 > NN) r1 = NN;
    float s = 0.f, s2 = 0.f;
    for (int r = r0 + half; r < r1; r += 2) {
        float v = X[(long)r * 128 + col];
        s += v; s2 += v * v;
    }
    ls[t] = s; ls2[t] = s2;
    __syncthreads();
    if (t < 128) {
        s  = ls[t]  + ls[t + 128];
        s2 = ls2[t] + ls2[t + 128];
        atomicAdd(&stats[col], s);
        atomicAdd(&stats[128 + col], s2);
    }
}

__global__ void k_bnfinal(const float* __restrict__ stats, const float* __restrict__ g,
                          const float* __restrict__ b, float* __restrict__ ss) {
    int c = threadIdx.x;
    if (c < 128) {
        float mean = stats[c] * (1.0f / NN);
        float var  = stats[128 + c] * (1.0f / NN) - mean * mean;
        float scale = g[c] * rsqrtf(var + BNEPS);
        ss[c] = scale;
        ss[128 + c] = b[c] - mean * scale;
    }
}

__global__ void k_bnrelu(const float* __restrict__ X, const float* __restrict__ ss,
                         float* __restrict__ Y) {
    int i = blockIdx.x * blockDim.x + threadIdx.x;
    int total = NN * HD / 4;
    int stride = gridDim.x * blockDim.x;
    for (; i < total; i += stride) {
        int c4 = (i & 31) * 4;
        float4 v = ((const float4*)X)[i];
        float4 sc = *(const float4*)&ss[c4];
        float4 sh = *(const float4*)&ss[128 + c4];
        float4 o;
        o.x = fmaxf(v.x * sc.x + sh.x, 0.f);
        o.y = fmaxf(v.y * sc.y + sh.y, 0.f);
        o.z = fmaxf(v.z * sc.z + sh.z, 0.f);
        o.w = fmaxf(v.w * sc.w + sh.w, 0.f);
        ((float4*)Y)[i] = o;
    }
}

// ---------------- attention scores: per gene  tanh(x@W1+b1)@w2 + b2 ----------------
__global__ void k_scores(const float* __restrict__ emb, const float* __restrict__ w1,
                         const float* __restrict__ b1, const float* __restrict__ w2,
                         const float* __restrict__ b2, float* __restrict__ scores) {
    __shared__ float wl[128 * 64];   // 32 KB
    __shared__ float w2l[64];
    int t = threadIdx.x;
    for (int i = t * 4; i < 128 * 64; i += 256 * 4)
        *(float4*)&wl[i] = *(const float4*)&w1[i];
    if (t < 64) w2l[t] = w2[t];
    __syncthreads();

    int lane = t & 63, wid = t >> 6;
    int gw = blockIdx.x * 4 + wid;
    int nw = gridDim.x * 4;
    float bias1 = b1[lane];
    float bias2 = b2[0];
    for (int g = gw; g < NN; g += nw) {
        const float* xr = emb + (long)g * 128;
        float xv0 = xr[lane];
        float xv1 = xr[64 + lane];
        float acc = bias1;
#pragma unroll
        for (int k = 0; k < 64; ++k)
            acc += __shfl(xv0, k) * wl[k * 64 + lane];
#pragma unroll
        for (int k = 0; k < 64; ++k)
            acc += __shfl(xv1, k) * wl[(64 + k) * 64 + lane];
        float v = tanhf(acc) * w2l[lane];
#pragma unroll
        for (int off = 32; off > 0; off >>= 1) v += __shfl_xor(v, off);
        if (lane == 0) scores[g] = v + bias2;
    }
}

// ---------------- softmax over genes within cell + weighted pool ----------------
__global__ void k_pool(const float* __restrict__ emb, const float* __restrict__ scores,
                       float* __restrict__ pooled) {
    __shared__ float sl[SUBG];
    __shared__ float red[128];
    int c = blockIdx.x;
    int t = threadIdx.x;   // 128 threads
    int base = c * SUBG;
    float lmax = -1e30f;
    for (int i = t; i < SUBG; i += 128) {
        float v = scores[base + i];
        sl[i] = v;
        lmax = fmaxf(lmax, v);
    }
    red[t] = lmax; __syncthreads();
    for (int off = 64; off > 0; off >>= 1) {
        if (t < off) red[t] = fmaxf(red[t], red[t + off]);
        __syncthreads();
    }
    float mx = red[0]; __syncthreads();
    float lsum = 0.f;
    for (int i = t; i < SUBG; i += 128) {
        float e = expf(sl[i] - mx);
        sl[i] = e;
        lsum += e;
    }
    red[t] = lsum; __syncthreads();
    for (int off = 64; off > 0; off >>= 1) {
        if (t < off) red[t] += red[t + off];
        __syncthreads();
    }
    float inv = 1.0f / red[0];
    float acc = 0.f;
    for (int s = 0; s < SUBG; ++s)
        acc += sl[s] * emb[(long)(base + s) * 128 + t];
    pooled[c * 128 + t] = acc * inv;
}

// ---------------- dense head ----------------
__global__ void k_head1(const float* __restrict__ pooled, const float* __restrict__ W,
                        const float* __restrict__ bias, float* __restrict__ Y) {
    __shared__ float row[128];
    int c = blockIdx.x, t = threadIdx.x;
    row[t] = pooled[c * 128 + t];
    __syncthreads();
    float acc = bias[t];
#pragma unroll 4
    for (int k = 0; k < 128; ++k) acc += row[k] * W[k * 128 + t];
    Y[c * 128 + t] = acc;
}

__global__ void k_headbn(const float* __restrict__ X, const float* __restrict__ g,
                         const float* __restrict__ b, float* __restrict__ Y, int cols) {
    int t = threadIdx.x;
    if (t >= cols) return;
    float s = 0.f, s2 = 0.f;
    for (int r = 0; r < CELLS; ++r) {
        float v = X[r * cols + t];
        s += v; s2 += v * v;
    }
    float mean = s * (1.0f / CELLS);
    float var = s2 * (1.0f / CELLS) - mean * mean;
    float scale = g[t] * rsqrtf(var + BNEPS);
    float shift = b[t] - mean * scale;
    for (int r = 0; r < CELLS; ++r)
        Y[r * cols + t] = fmaxf(X[r * cols + t] * scale + shift, 0.f);
}

__global__ void k_head2(const float* __restrict__ Y1, const float* __restrict__ W,
                        const float* __restrict__ bias, float* __restrict__ Y2) {
    __shared__ float row[128];
    int c = blockIdx.x, t = threadIdx.x;   // 128 threads
    row[t] = Y1[c * 128 + t];
    __syncthreads();
    if (t < 32) {
        float acc = bias[t];
#pragma unroll 4
        for (int k = 0; k < 128; ++k) acc += row[k] * W[k * 32 + t];
        Y2[c * 32 + t] = acc;
    }
}

// ---------------- launcher ----------------
extern "C" void kernel_launch(void* const* d_in, const int* in_sizes, int n_in,
                              void* d_out, int out_size, void* d_ws, size_t ws_size,
                              hipStream_t stream) {
    const float* x        = (const float*)d_in[0];
    const int*   ei       = (const int*)d_in[1];
    const float* conv1_w  = (const float*)d_in[2];
    const float* conv1_b  = (const float*)d_in[3];
    const float* bn1_g    = (const float*)d_in[4];
    const float* bn1_b    = (const float*)d_in[5];
    const float* conv2_w  = (const float*)d_in[6];
    const float* conv2_b  = (const float*)d_in[7];
    const float* bn2_g    = (const float*)d_in[8];
    const float* bn2_b    = (const float*)d_in[9];
    const float* att_w1   = (const float*)d_in[10];
    const float* att_b1   = (const float*)d_in[11];
    const float* att_w2   = (const float*)d_in[12];
    const float* att_b2   = (const float*)d_in[13];
    const float* fc_w     = (const float*)d_in[14];
    const float* fc_b     = (const float*)d_in[15];
    const float* bne_g    = (const float*)d_in[16];
    const float* bne_b    = (const float*)d_in[17];
    const float* bot_w    = (const float*)d_in[18];
    const float* bot_b    = (const float*)d_in[19];
    const float* bnb_g    = (const float*)d_in[20];
    const float* bnb_b    = (const float*)d_in[21];

    const int* src = ei;
    const int* dst = ei + EE;

    float* y_out   = (float*)d_out;            // [100,32]
    float* emb_out = y_out + CELLS * 32;       // [40000,128]

    float* ws = (float*)d_ws;
    float* bufA   = ws;                        // N*H
    float* bufB   = bufA + (long)NN * HD;      // N*H
    float* dis    = bufB + (long)NN * HD;      // N
    float* scores = dis + NN;                  // N
    float* stats  = scores + NN;               // 256
    float* sstats = stats + 256;               // 256
    float* pooled = sstats + 256;              // C*H
    float* y1pre  = pooled + CELLS * HD;       // C*H
    float* y1     = y1pre + CELLS * HD;        // C*H
    float* y2pre  = y1 + CELLS * HD;           // C*32

    // degree -> deg^{-1/2}
    k_deg_init<<<(NN + 255) / 256, 256, 0, stream>>>(dis);
    k_deg_count<<<2048, 256, 0, stream>>>(dst, dis);
    k_dis<<<(NN + 255) / 256, 256, 0, stream>>>(dis);

    // ---- conv1 ----
    k_gemm128<<<1024, 256, 0, stream>>>(x, conv1_w, bufA, NN);
    k_selfloop_bias<<<4096, 256, 0, stream>>>(bufA, dis, conv1_b, bufB);
    k_scatter<<<8192, 256, 0, stream>>>(bufA, src, dst, dis, bufB);
    k_zero<<<1, 256, 0, stream>>>(stats, 256);
    k_bnstats<<<160, 256, 0, stream>>>(bufB, stats, 250);
    k_bnfinal<<<1, 128, 0, stream>>>(stats, bn1_g, bn1_b, sstats);
    k_bnrelu<<<4096, 256, 0, stream>>>(bufB, sstats, bufA);

    // ---- conv2 ----
    k_gemm128<<<1024, 256, 0, stream>>>(bufA, conv2_w, bufB, NN);
    k_selfloop_bias<<<4096, 256, 0, stream>>>(bufB, dis, conv2_b, bufA);
    k_scatter<<<8192, 256, 0, stream>>>(bufB, src, dst, dis, bufA);
    k_zero<<<1, 256, 0, stream>>>(stats, 256);
    k_bnstats<<<160, 256, 0, stream>>>(bufA, stats, 250);
    k_bnfinal<<<1, 128, 0, stream>>>(stats, bn2_g, bn2_b, sstats);
    k_bnrelu<<<4096, 256, 0, stream>>>(bufA, sstats, emb_out);

    // ---- attention pooling ----
    k_scores<<<1024, 256, 0, stream>>>(emb_out, att_w1, att_b1, att_w2, att_b2, scores);
    k_pool<<<CELLS, 128, 0, stream>>>(emb_out, scores, pooled);

    // ---- head ----
    k_head1<<<CELLS, 128, 0, stream>>>(pooled, fc_w, fc_b, y1pre);
    k_headbn<<<1, 128, 0, stream>>>(y1pre, bne_g, bne_b, y1, 128);
    k_head2<<<CELLS, 128, 0, stream>>>(y1, bot_w, bot_b, y2pre);
    k_headbn<<<1, 64, 0, stream>>>(y2pre, bnb_g, bnb_b, y_out, 32);
}

// Round 2
// 1363.565 us; speedup vs baseline: 1.6481x; 1.6481x over previous
//
#include <hip/hip_runtime.h>
#include <math.h>

#define NN   40000
#define EE   640000
#define FD   128
#define HD   128
#define SUBG 400
#define CELLS 100
#define BNEPS 1e-5f
#define NPB  157   // ceil(NN/256)

// ---------------- CSR build ----------------
__global__ void k_zeroi(int* p, int n) {
    int i = blockIdx.x * blockDim.x + threadIdx.x;
    if (i < n) p[i] = 0;
}

__global__ void k_degcount(const int* __restrict__ dst, int* __restrict__ deg) {
    int i = blockIdx.x * blockDim.x + threadIdx.x;
    int stride = gridDim.x * blockDim.x;
    for (; i < EE; i += stride) atomicAdd(&deg[dst[i]], 1);
}

// per-block exclusive scan + block sums
__global__ void k_scan1(const int* __restrict__ deg, int* __restrict__ excl,
                        int* __restrict__ part) {
    __shared__ int s[256];
    int t = threadIdx.x;
    int i = blockIdx.x * 256 + t;
    int v = (i < NN) ? deg[i] : 0;
    s[t] = v;
    __syncthreads();
    for (int off = 1; off < 256; off <<= 1) {
        int add = (t >= off) ? s[t - off] : 0;
        __syncthreads();
        s[t] += add;
        __syncthreads();
    }
    if (i < NN) excl[i] = s[t] - v;
    if (t == 255) part[blockIdx.x] = s[255];
}

__global__ void k_scan2(int* __restrict__ part, int* __restrict__ partx) {
    __shared__ int s[256];
    int t = threadIdx.x;
    int v = (t < NPB) ? part[t] : 0;
    s[t] = v;
    __syncthreads();
    for (int off = 1; off < 256; off <<= 1) {
        int add = (t >= off) ? s[t - off] : 0;
        __syncthreads();
        s[t] += add;
        __syncthreads();
    }
    if (t < NPB) partx[t] = s[t] - v;
}

__global__ void k_scan3(const int* __restrict__ excl, const int* __restrict__ partx,
                        const int* __restrict__ deg, int* __restrict__ rowstart,
                        float* __restrict__ dis) {
    int i = blockIdx.x * 256 + threadIdx.x;
    if (i < NN) {
        rowstart[i] = excl[i] + partx[blockIdx.x];
        dis[i] = rsqrtf((float)(deg[i] + 1));   // +1 self-loop
    }
    if (i == 0) rowstart[NN] = EE;
}

__global__ void k_fill(const int* __restrict__ src, const int* __restrict__ dst,
                       const int* __restrict__ rowstart, int* __restrict__ cursor,
                       int* __restrict__ csr_src) {
    int i = blockIdx.x * blockDim.x + threadIdx.x;
    int stride = gridDim.x * blockDim.x;
    for (; i < EE; i += stride) {
        int d = dst[i];
        int slot = rowstart[d] + atomicAdd(&cursor[d], 1);
        csr_src[slot] = src[i];
    }
}

// ---------------- dense GEMM  Y[M,128] = X[M,128] @ W[128,128] ----------------
__global__ void k_gemm128(const float* __restrict__ X, const float* __restrict__ W,
                          float* __restrict__ Y, int M) {
    __shared__ float wl[FD * HD];   // 64 KB
    int t = threadIdx.x;
    for (int i = t * 4; i < FD * HD; i += 256 * 4)
        *(float4*)&wl[i] = *(const float4*)&W[i];
    __syncthreads();

    int lane = t & 63;
    int wid  = t >> 6;
    int gw = blockIdx.x * 4 + wid;
    int nw = gridDim.x * 4;
    for (int row = gw; row < M; row += nw) {
        const float* xr = X + (long)row * 128;
        float xv0 = xr[lane];
        float xv1 = xr[64 + lane];
        float2 acc = {0.f, 0.f};
#pragma unroll
        for (int k = 0; k < 64; ++k) {
            float xk = __shfl(xv0, k);
            float2 w = *(const float2*)&wl[k * 128 + 2 * lane];
            acc.x += xk * w.x; acc.y += xk * w.y;
        }
#pragma unroll
        for (int k = 0; k < 64; ++k) {
            float xk = __shfl(xv1, k);
            float2 w = *(const float2*)&wl[(64 + k) * 128 + 2 * lane];
            acc.x += xk * w.x; acc.y += xk * w.y;
        }
        *(float2*)&Y[(long)row * 128 + 2 * lane] = acc;
    }
}

// ---------------- GCN aggregation: CSR gather, fused self-loop + bias ----------------
// out[d,:] = dis[d] * ( sum_{s in N(d)} dis[s]*h[s,:] + dis[d]*h[d,:] ) + bias
__global__ void k_gather(const float* __restrict__ Hm, const int* __restrict__ rowstart,
                         const int* __restrict__ csr_src, const float* __restrict__ dis,
                         const float* __restrict__ bias, float* __restrict__ out) {
    int lane = threadIdx.x & 63;
    int node = (blockIdx.x * blockDim.x + threadIdx.x) >> 6;
    if (node >= NN) return;
    float dd = dis[node];
    float2 h0 = *(const float2*)&Hm[(long)node * 128 + 2 * lane];
    float2 acc = { h0.x * dd, h0.y * dd };
    int e  = rowstart[node];
    int e1 = rowstart[node + 1];
    for (; e + 1 < e1; e += 2) {
        int s0 = csr_src[e], s1 = csr_src[e + 1];
        float d0 = dis[s0], d1 = dis[s1];
        float2 v0 = *(const float2*)&Hm[(long)s0 * 128 + 2 * lane];
        float2 v1 = *(const float2*)&Hm[(long)s1 * 128 + 2 * lane];
        acc.x += v0.x * d0; acc.y += v0.y * d0;
        acc.x += v1.x * d1; acc.y += v1.y * d1;
    }
    if (e < e1) {
        int s0 = csr_src[e];
        float d0 = dis[s0];
        float2 v0 = *(const float2*)&Hm[(long)s0 * 128 + 2 * lane];
        acc.x += v0.x * d0; acc.y += v0.y * d0;
    }
    float2 b2 = *(const float2*)&bias[2 * lane];
    float2 o = { acc.x * dd + b2.x, acc.y * dd + b2.y };
    *(float2*)&out[(long)node * 128 + 2 * lane] = o;
}

// ---------------- BatchNorm (batch stats over N rows, 128 cols) ----------------
__global__ void k_zero(float* p, int n) {
    int i = blockIdx.x * blockDim.x + threadIdx.x;
    if (i < n) p[i] = 0.f;
}

__global__ void k_bnstats(const float* __restrict__ X, float* __restrict__ stats,
                          int rowsPerBlock) {
    __shared__ float ls[256], ls2[256];
    int t = threadIdx.x;
    int col = t & 127, half = t >> 7;
    int r0 = blockIdx.x * rowsPerBlock;
    int r1 = r0 + rowsPerBlock; if (r1 > NN) r1 = NN;
    float s = 0.f, s2 = 0.f;
    for (int r = r0 + half; r < r1; r += 2) {
        float v = X[(long)r * 128 + col];
        s += v; s2 += v * v;
    }
    ls[t] = s; ls2[t] = s2;
    __syncthreads();
    if (t < 128) {
        s  = ls[t]  + ls[t + 128];
        s2 = ls2[t] + ls2[t + 128];
        atomicAdd(&stats[col], s);
        atomicAdd(&stats[128 + col], s2);
    }
}

__global__ void k_bnfinal(const float* __restrict__ stats, const float* __restrict__ g,
                          const float* __restrict__ b, float* __restrict__ ss) {
    int c = threadIdx.x;
    if (c < 128) {
        float mean = stats[c] * (1.0f / NN);
        float var  = stats[128 + c] * (1.0f / NN) - mean * mean;
        float scale = g[c] * rsqrtf(var + BNEPS);
        ss[c] = scale;
        ss[128 + c] = b[c] - mean * scale;
    }
}

__global__ void k_bnrelu(const float* __restrict__ X, const float* __restrict__ ss,
                         float* __restrict__ Y) {
    int i = blockIdx.x * blockDim.x + threadIdx.x;
    int total = NN * HD / 4;
    int stride = gridDim.x * blockDim.x;
    for (; i < total; i += stride) {
        int c4 = (i & 31) * 4;
        float4 v = ((const float4*)X)[i];
        float4 sc = *(const float4*)&ss[c4];
        float4 sh = *(const float4*)&ss[128 + c4];
        float4 o;
        o.x = fmaxf(v.x * sc.x + sh.x, 0.f);
        o.y = fmaxf(v.y * sc.y + sh.y, 0.f);
        o.z = fmaxf(v.z * sc.z + sh.z, 0.f);
        o.w = fmaxf(v.w * sc.w + sh.w, 0.f);
        ((float4*)Y)[i] = o;
    }
}

// ---------------- attention scores: per gene  tanh(x@W1+b1)@w2 + b2 ----------------
__global__ void k_scores(const float* __restrict__ emb, const float* __restrict__ w1,
                         const float* __restrict__ b1, const float* __restrict__ w2,
                         const float* __restrict__ b2, float* __restrict__ scores) {
    __shared__ float wl[128 * 64];   // 32 KB
    __shared__ float w2l[64];
    int t = threadIdx.x;
    for (int i = t * 4; i < 128 * 64; i += 256 * 4)
        *(float4*)&wl[i] = *(const float4*)&w1[i];
    if (t < 64) w2l[t] = w2[t];
    __syncthreads();

    int lane = t & 63, wid = t >> 6;
    int gw = blockIdx.x * 4 + wid;
    int nw = gridDim.x * 4;
    float bias1 = b1[lane];
    float bias2 = b2[0];
    for (int g = gw; g < NN; g += nw) {
        const float* xr = emb + (long)g * 128;
        float xv0 = xr[lane];
        float xv1 = xr[64 + lane];
        float acc = bias1;
#pragma unroll
        for (int k = 0; k < 64; ++k)
            acc += __shfl(xv0, k) * wl[k * 64 + lane];
#pragma unroll
        for (int k = 0; k < 64; ++k)
            acc += __shfl(xv1, k) * wl[(64 + k) * 64 + lane];
        float v = tanhf(acc) * w2l[lane];
#pragma unroll
        for (int off = 32; off > 0; off >>= 1) v += __shfl_xor(v, off);
        if (lane == 0) scores[g] = v + bias2;
    }
}

// ---------------- softmax over genes within cell + weighted pool ----------------
__global__ void k_pool(const float* __restrict__ emb, const float* __restrict__ scores,
                       float* __restrict__ pooled) {
    __shared__ float sl[SUBG];
    __shared__ float red[512];
    int c = blockIdx.x;
    int t = threadIdx.x;   // 512 threads
    int base = c * SUBG;
    float lmax = -1e30f;
    for (int i = t; i < SUBG; i += 512) {
        float v = scores[base + i];
        sl[i] = v;
        lmax = fmaxf(lmax, v);
    }
    red[t] = lmax; __syncthreads();
    for (int off = 256; off > 0; off >>= 1) {
        if (t < off) red[t] = fmaxf(red[t], red[t + off]);
        __syncthreads();
    }
    float mx = red[0]; __syncthreads();
    float lsum = 0.f;
    for (int i = t; i < SUBG; i += 512) {
        float e = __expf(sl[i] - mx);
        sl[i] = e;
        lsum += e;
    }
    red[t] = lsum; __syncthreads();
    for (int off = 256; off > 0; off >>= 1) {
        if (t < off) red[t] += red[t + off];
        __syncthreads();
    }
    float inv = 1.0f / red[0];
    __syncthreads();
    int col = t & 127, grp = t >> 7;   // 4 row-groups
    float acc = 0.f;
    for (int s = grp; s < SUBG; s += 4)
        acc += sl[s] * emb[(long)(base + s) * 128 + col];
    red[t] = acc; __syncthreads();
    if (grp == 0)
        pooled[c * 128 + col] = (red[col] + red[128 + col] + red[256 + col] + red[384 + col]) * inv;
}

// ---------------- dense head ----------------
__global__ void k_head1(const float* __restrict__ pooled, const float* __restrict__ W,
                        const float* __restrict__ bias, float* __restrict__ Y) {
    __shared__ float row[128];
    int c = blockIdx.x, t = threadIdx.x;
    row[t] = pooled[c * 128 + t];
    __syncthreads();
    float acc = bias[t];
#pragma unroll 4
    for (int k = 0; k < 128; ++k) acc += row[k] * W[k * 128 + t];
    Y[c * 128 + t] = acc;
}

__global__ void k_headbn(const float* __restrict__ X, const float* __restrict__ g,
                         const float* __restrict__ b, float* __restrict__ Y, int cols) {
    int t = threadIdx.x;
    if (t >= cols) return;
    float s = 0.f, s2 = 0.f;
    for (int r = 0; r < CELLS; ++r) {
        float v = X[r * cols + t];
        s += v; s2 += v * v;
    }
    float mean = s * (1.0f / CELLS);
    float var = s2 * (1.0f / CELLS) - mean * mean;
    float scale = g[t] * rsqrtf(var + BNEPS);
    float shift = b[t] - mean * scale;
    for (int r = 0; r < CELLS; ++r)
        Y[r * cols + t] = fmaxf(X[r * cols + t] * scale + shift, 0.f);
}

__global__ void k_head2(const float* __restrict__ Y1, const float* __restrict__ W,
                        const float* __restrict__ bias, float* __restrict__ Y2) {
    __shared__ float row[128];
    int c = blockIdx.x, t = threadIdx.x;   // 128 threads
    row[t] = Y1[c * 128 + t];
    __syncthreads();
    if (t < 32) {
        float acc = bias[t];
#pragma unroll 4
        for (int k = 0; k < 128; ++k) acc += row[k] * W[k * 32 + t];
        Y2[c * 32 + t] = acc;
    }
}

// ---------------- launcher ----------------
extern "C" void kernel_launch(void* const* d_in, const int* in_sizes, int n_in,
                              void* d_out, int out_size, void* d_ws, size_t ws_size,
                              hipStream_t stream) {
    const float* x        = (const float*)d_in[0];
    const int*   ei       = (const int*)d_in[1];
    const float* conv1_w  = (const float*)d_in[2];
    const float* conv1_b  = (const float*)d_in[3];
    const float* bn1_g    = (const float*)d_in[4];
    const float* bn1_b    = (const float*)d_in[5];
    const float* conv2_w  = (const float*)d_in[6];
    const float* conv2_b  = (const float*)d_in[7];
    const float* bn2_g    = (const float*)d_in[8];
    const float* bn2_b    = (const float*)d_in[9];
    const float* att_w1   = (const float*)d_in[10];
    const float* att_b1   = (const float*)d_in[11];
    const float* att_w2   = (const float*)d_in[12];
    const float* att_b2   = (const float*)d_in[13];
    const float* fc_w     = (const float*)d_in[14];
    const float* fc_b     = (const float*)d_in[15];
    const float* bne_g    = (const float*)d_in[16];
    const float* bne_b    = (const float*)d_in[17];
    const float* bot_w    = (const float*)d_in[18];
    const float* bot_b    = (const float*)d_in[19];
    const float* bnb_g    = (const float*)d_in[20];
    const float* bnb_b    = (const float*)d_in[21];

    const int* src = ei;
    const int* dst = ei + EE;

    float* y_out   = (float*)d_out;            // [100,32]
    float* emb_out = y_out + CELLS * 32;       // [40000,128]

    float* ws = (float*)d_ws;
    float* bufA   = ws;                        // N*H
    float* bufB   = bufA + (long)NN * HD;      // N*H
    float* dis    = bufB + (long)NN * HD;      // N
    float* scores = dis + NN;                  // N
    float* stats  = scores + NN;               // 256
    float* sstats = stats + 256;               // 256
    float* pooled = sstats + 256;              // C*H
    float* y1pre  = pooled + CELLS * HD;       // C*H
    float* y1     = y1pre + CELLS * HD;        // C*H
    float* y2pre  = y1 + CELLS * HD;           // C*32
    int* ibase    = (int*)(y2pre + CELLS * 32);
    int* deg      = ibase;                     // N   (deg and cursor adjacent -> one zero pass)
    int* cursor   = deg + NN;                  // N
    int* excl     = cursor + NN;               // N
    int* rowstart = excl + NN;                 // N+1
    int* part     = rowstart + NN + 1;         // NPB
    int* partx    = part + NPB;                // NPB
    int* csr_src  = partx + NPB;               // E

    // ---- CSR build (shared by both convs) ----
    k_zeroi<<<(2 * NN + 255) / 256, 256, 0, stream>>>(deg, 2 * NN);  // deg + cursor
    k_degcount<<<1024, 256, 0, stream>>>(dst, deg);
    k_scan1<<<NPB, 256, 0, stream>>>(deg, excl, part);
    k_scan2<<<1, 256, 0, stream>>>(part, partx);
    k_scan3<<<NPB, 256, 0, stream>>>(excl, partx, deg, rowstart, dis);
    k_fill<<<2048, 256, 0, stream>>>(src, dst, rowstart, cursor, csr_src);

    // ---- conv1 ----
    k_gemm128<<<1024, 256, 0, stream>>>(x, conv1_w, bufA, NN);
    k_gather<<<10000, 256, 0, stream>>>(bufA, rowstart, csr_src, dis, conv1_b, bufB);
    k_zero<<<1, 256, 0, stream>>>(stats, 256);
    k_bnstats<<<160, 256, 0, stream>>>(bufB, stats, 250);
    k_bnfinal<<<1, 128, 0, stream>>>(stats, bn1_g, bn1_b, sstats);
    k_bnrelu<<<4096, 256, 0, stream>>>(bufB, sstats, bufA);

    // ---- conv2 ----
    k_gemm128<<<1024, 256, 0, stream>>>(bufA, conv2_w, bufB, NN);
    k_gather<<<10000, 256, 0, stream>>>(bufB, rowstart, csr_src, dis, conv2_b, bufA);
    k_zero<<<1, 256, 0, stream>>>(stats, 256);
    k_bnstats<<<160, 256, 0, stream>>>(bufA, stats, 250);
    k_bnfinal<<<1, 128, 0, stream>>>(stats, bn2_g, bn2_b, sstats);
    k_bnrelu<<<4096, 256, 0, stream>>>(bufA, sstats, emb_out);

    // ---- attention pooling ----
    k_scores<<<1024, 256, 0, stream>>>(emb_out, att_w1, att_b1, att_w2, att_b2, scores);
    k_pool<<<CELLS, 512, 0, stream>>>(emb_out, scores, pooled);

    // ---- head ----
    k_head1<<<CELLS, 128, 0, stream>>>(pooled, fc_w, fc_b, y1pre);
    k_headbn<<<1, 128, 0, stream>>>(y1pre, bne_g, bne_b, y1, 128);
    k_head2<<<CELLS, 128, 0, stream>>>(y1, bot_w, bot_b, y2pre);
    k_headbn<<<1, 64, 0, stream>>>(y2pre, bnb_g, bnb_b, y_out, 32);
}

// Round 3
// 433.811 us; speedup vs baseline: 5.1803x; 3.1432x over previous
//
#include <hip/hip_runtime.h>
#include <math.h>

#define NN   40000
#define EE   640000
#define FD   128
#define HD   128
#define SUBG 400
#define CELLS 100
#define BNEPS 1e-5f
#define NPB  157   // ceil(NN/256)

// ---------------- CSR build ----------------
__global__ void k_zeroi(int* p, int n) {
    int i = blockIdx.x * blockDim.x + threadIdx.x;
    if (i < n) p[i] = 0;
}

__global__ void k_degcount(const int* __restrict__ dst, int* __restrict__ deg) {
    int i = blockIdx.x * blockDim.x + threadIdx.x;
    int stride = gridDim.x * blockDim.x;
    for (; i < EE; i += stride) atomicAdd(&deg[dst[i]], 1);
}

__global__ void k_scan1(const int* __restrict__ deg, int* __restrict__ excl,
                        int* __restrict__ part) {
    __shared__ int s[256];
    int t = threadIdx.x;
    int i = blockIdx.x * 256 + t;
    int v = (i < NN) ? deg[i] : 0;
    s[t] = v;
    __syncthreads();
    for (int off = 1; off < 256; off <<= 1) {
        int add = (t >= off) ? s[t - off] : 0;
        __syncthreads();
        s[t] += add;
        __syncthreads();
    }
    if (i < NN) excl[i] = s[t] - v;
    if (t == 255) part[blockIdx.x] = s[255];
}

__global__ void k_scan2(int* __restrict__ part, int* __restrict__ partx) {
    __shared__ int s[256];
    int t = threadIdx.x;
    int v = (t < NPB) ? part[t] : 0;
    s[t] = v;
    __syncthreads();
    for (int off = 1; off < 256; off <<= 1) {
        int add = (t >= off) ? s[t - off] : 0;
        __syncthreads();
        s[t] += add;
        __syncthreads();
    }
    if (t < NPB) partx[t] = s[t] - v;
}

__global__ void k_scan3(const int* __restrict__ excl, const int* __restrict__ partx,
                        const int* __restrict__ deg, int* __restrict__ rowstart,
                        float* __restrict__ dis) {
    int i = blockIdx.x * 256 + threadIdx.x;
    if (i < NN) {
        rowstart[i] = excl[i] + partx[blockIdx.x];
        dis[i] = rsqrtf((float)(deg[i] + 1));   // +1 self-loop
    }
    if (i == 0) rowstart[NN] = EE;
}

__global__ void k_fill(const int* __restrict__ src, const int* __restrict__ dst,
                       const int* __restrict__ rowstart, int* __restrict__ cursor,
                       int* __restrict__ csr_src) {
    int i = blockIdx.x * blockDim.x + threadIdx.x;
    int stride = gridDim.x * blockDim.x;
    for (; i < EE; i += stride) {
        int d = dst[i];
        int slot = rowstart[d] + atomicAdd(&cursor[d], 1);
        csr_src[slot] = src[i];
    }
}

// ---------------- tiled GEMM  Y[M,128] = X[M,128] @ W[128,128] ----------------
// 64-row tile in LDS; thread (rg,c) computes 32 rows x 1 col.
// Optional fused input BN+ReLU during staging (ss != nullptr).
__global__ void k_gemm128(const float* __restrict__ X, const float* __restrict__ W,
                          float* __restrict__ Y, const float* __restrict__ ss) {
    __shared__ float xs[64 * 128];   // 32 KB
    int t = threadIdx.x;
    long rowbase = (long)blockIdx.x * 64;
    const float4* Xv = (const float4*)(X + rowbase * 128);
    float4* xsv = (float4*)xs;
    if (ss) {
#pragma unroll
        for (int i = 0; i < 8; ++i) {
            int f = t + 256 * i;
            int c4 = (f & 31) * 4;
            float4 v = Xv[f];
            float4 sc = *(const float4*)&ss[c4];
            float4 sh = *(const float4*)&ss[128 + c4];
            v.x = fmaxf(v.x * sc.x + sh.x, 0.f);
            v.y = fmaxf(v.y * sc.y + sh.y, 0.f);
            v.z = fmaxf(v.z * sc.z + sh.z, 0.f);
            v.w = fmaxf(v.w * sc.w + sh.w, 0.f);
            xsv[f] = v;
        }
    } else {
#pragma unroll
        for (int i = 0; i < 8; ++i)
            xsv[t + 256 * i] = Xv[t + 256 * i];
    }
    __syncthreads();

    int c = t & 127;
    int rbase = (t >> 7) * 32;
    const float* xrow = xs + rbase * 128;
    float acc[32];
#pragma unroll
    for (int r = 0; r < 32; ++r) acc[r] = 0.f;

    for (int k4 = 0; k4 < 32; ++k4) {
        float w0 = W[(k4 * 4 + 0) * 128 + c];
        float w1 = W[(k4 * 4 + 1) * 128 + c];
        float w2 = W[(k4 * 4 + 2) * 128 + c];
        float w3 = W[(k4 * 4 + 3) * 128 + c];
#pragma unroll
        for (int r = 0; r < 32; ++r) {
            float4 x4 = *(const float4*)&xrow[r * 128 + k4 * 4];
            acc[r] = fmaf(x4.x, w0, acc[r]);
            acc[r] = fmaf(x4.y, w1, acc[r]);
            acc[r] = fmaf(x4.z, w2, acc[r]);
            acc[r] = fmaf(x4.w, w3, acc[r]);
        }
    }
    float* yout = Y + (rowbase + rbase) * 128 + c;
#pragma unroll
    for (int r = 0; r < 32; ++r)
        yout[r * 128] = acc[r];
}

// ---------------- GCN aggregation: CSR gather, fused self-loop + bias ----------------
__global__ void k_gather(const float* __restrict__ Hm, const int* __restrict__ rowstart,
                         const int* __restrict__ csr_src, const float* __restrict__ dis,
                         const float* __restrict__ bias, float* __restrict__ out) {
    int lane = threadIdx.x & 63;
    int node = (blockIdx.x * blockDim.x + threadIdx.x) >> 6;
    if (node >= NN) return;
    float dd = dis[node];
    float2 h0 = *(const float2*)&Hm[(long)node * 128 + 2 * lane];
    float2 acc = { h0.x * dd, h0.y * dd };
    int e  = rowstart[node];
    int e1 = rowstart[node + 1];
    for (; e + 1 < e1; e += 2) {
        int s0 = csr_src[e], s1 = csr_src[e + 1];
        float d0 = dis[s0], d1 = dis[s1];
        float2 v0 = *(const float2*)&Hm[(long)s0 * 128 + 2 * lane];
        float2 v1 = *(const float2*)&Hm[(long)s1 * 128 + 2 * lane];
        acc.x += v0.x * d0; acc.y += v0.y * d0;
        acc.x += v1.x * d1; acc.y += v1.y * d1;
    }
    if (e < e1) {
        int s0 = csr_src[e];
        float d0 = dis[s0];
        float2 v0 = *(const float2*)&Hm[(long)s0 * 128 + 2 * lane];
        acc.x += v0.x * d0; acc.y += v0.y * d0;
    }
    float2 b2 = *(const float2*)&bias[2 * lane];
    float2 o = { acc.x * dd + b2.x, acc.y * dd + b2.y };
    *(float2*)&out[(long)node * 128 + 2 * lane] = o;
}

// ---------------- BatchNorm ----------------
__global__ void k_zero(float* p, int n) {
    int i = blockIdx.x * blockDim.x + threadIdx.x;
    if (i < n) p[i] = 0.f;
}

__global__ void k_bnstats(const float* __restrict__ X, float* __restrict__ stats,
                          int rowsPerBlock) {
    __shared__ float ls[256], ls2[256];
    int t = threadIdx.x;
    int col = t & 127, half = t >> 7;
    int r0 = blockIdx.x * rowsPerBlock;
    int r1 = r0 + rowsPerBlock; if (r1 > NN) r1 = NN;
    float s = 0.f, s2 = 0.f;
    for (int r = r0 + half; r < r1; r += 2) {
        float v = X[(long)r * 128 + col];
        s += v; s2 += v * v;
    }
    ls[t] = s; ls2[t] = s2;
    __syncthreads();
    if (t < 128) {
        s  = ls[t]  + ls[t + 128];
        s2 = ls2[t] + ls2[t + 128];
        atomicAdd(&stats[col], s);
        atomicAdd(&stats[128 + col], s2);
    }
}

__global__ void k_bnfinal(const float* __restrict__ stats, const float* __restrict__ g,
                          const float* __restrict__ b, float* __restrict__ ss) {
    int c = threadIdx.x;
    if (c < 128) {
        float mean = stats[c] * (1.0f / NN);
        float var  = stats[128 + c] * (1.0f / NN) - mean * mean;
        float scale = g[c] * rsqrtf(var + BNEPS);
        ss[c] = scale;
        ss[128 + c] = b[c] - mean * scale;
    }
}

__global__ void k_bnrelu(const float* __restrict__ X, const float* __restrict__ ss,
                         float* __restrict__ Y) {
    int i = blockIdx.x * blockDim.x + threadIdx.x;
    int total = NN * HD / 4;
    int stride = gridDim.x * blockDim.x;
    for (; i < total; i += stride) {
        int c4 = (i & 31) * 4;
        float4 v = ((const float4*)X)[i];
        float4 sc = *(const float4*)&ss[c4];
        float4 sh = *(const float4*)&ss[128 + c4];
        float4 o;
        o.x = fmaxf(v.x * sc.x + sh.x, 0.f);
        o.y = fmaxf(v.y * sc.y + sh.y, 0.f);
        o.z = fmaxf(v.z * sc.z + sh.z, 0.f);
        o.w = fmaxf(v.w * sc.w + sh.w, 0.f);
        ((float4*)Y)[i] = o;
    }
}

// ---------------- attention scores (tiled): tanh(x@W1+b1)@w2 + b2 ----------------
__global__ void k_scores(const float* __restrict__ emb, const float* __restrict__ w1,
                         const float* __restrict__ b1, const float* __restrict__ w2,
                         const float* __restrict__ b2, float* __restrict__ scores) {
    __shared__ float xs[64 * 128];  // 32 KB
    int t = threadIdx.x;
    long rowbase = (long)blockIdx.x * 64;
    const float4* Xv = (const float4*)(emb + rowbase * 128);
    float4* xsv = (float4*)xs;
#pragma unroll
    for (int i = 0; i < 8; ++i)
        xsv[t + 256 * i] = Xv[t + 256 * i];
    __syncthreads();

    int lane = t & 63;
    int wv = t >> 6;            // wave 0..3 -> rows wv*16 .. +15
    int rbase = wv * 16;
    const float* xrow = xs + rbase * 128;
    float bias1 = b1[lane];
    float acc[16];
#pragma unroll
    for (int r = 0; r < 16; ++r) acc[r] = bias1;

    for (int k4 = 0; k4 < 32; ++k4) {
        float w0 = w1[(k4 * 4 + 0) * 64 + lane];
        float w1v = w1[(k4 * 4 + 1) * 64 + lane];
        float w2v_ = w1[(k4 * 4 + 2) * 64 + lane];
        float w3 = w1[(k4 * 4 + 3) * 64 + lane];
#pragma unroll
        for (int r = 0; r < 16; ++r) {
            float4 x4 = *(const float4*)&xrow[r * 128 + k4 * 4];
            acc[r] = fmaf(x4.x, w0, acc[r]);
            acc[r] = fmaf(x4.y, w1v, acc[r]);
            acc[r] = fmaf(x4.z, w2v_, acc[r]);
            acc[r] = fmaf(x4.w, w3, acc[r]);
        }
    }
    float w2l = w2[lane];
    float b2v = b2[0];
#pragma unroll
    for (int r = 0; r < 16; ++r) {
        float v = tanhf(acc[r]) * w2l;
#pragma unroll
        for (int off = 32; off > 0; off >>= 1) v += __shfl_xor(v, off);
        if (lane == 0) scores[rowbase + rbase + r] = v + b2v;
    }
}

// ---------------- softmax over genes within cell + weighted pool ----------------
__global__ void k_pool(const float* __restrict__ emb, const float* __restrict__ scores,
                       float* __restrict__ pooled) {
    __shared__ float sl[SUBG];
    __shared__ float red[512];
    int c = blockIdx.x;
    int t = threadIdx.x;   // 512 threads
    int base = c * SUBG;
    float lmax = -1e30f;
    for (int i = t; i < SUBG; i += 512) {
        float v = scores[base + i];
        sl[i] = v;
        lmax = fmaxf(lmax, v);
    }
    red[t] = lmax; __syncthreads();
    for (int off = 256; off > 0; off >>= 1) {
        if (t < off) red[t] = fmaxf(red[t], red[t + off]);
        __syncthreads();
    }
    float mx = red[0]; __syncthreads();
    float lsum = 0.f;
    for (int i = t; i < SUBG; i += 512) {
        float e = __expf(sl[i] - mx);
        sl[i] = e;
        lsum += e;
    }
    red[t] = lsum; __syncthreads();
    for (int off = 256; off > 0; off >>= 1) {
        if (t < off) red[t] += red[t + off];
        __syncthreads();
    }
    float inv = 1.0f / red[0];
    __syncthreads();
    int col = t & 127, grp = t >> 7;   // 4 row-groups
    float acc = 0.f;
#pragma unroll 2
    for (int s = grp; s < SUBG; s += 4)
        acc += sl[s] * emb[(long)(base + s) * 128 + col];
    red[t] = acc; __syncthreads();
    if (grp == 0)
        pooled[c * 128 + col] = (red[col] + red[128 + col] + red[256 + col] + red[384 + col]) * inv;
}

// ---------------- dense head ----------------
__global__ void k_head1(const float* __restrict__ pooled, const float* __restrict__ W,
                        const float* __restrict__ bias, float* __restrict__ Y) {
    __shared__ float row[128];
    int c = blockIdx.x, t = threadIdx.x;
    row[t] = pooled[c * 128 + t];
    __syncthreads();
    float acc = bias[t];
#pragma unroll 4
    for (int k = 0; k < 128; ++k) acc += row[k] * W[k * 128 + t];
    Y[c * 128 + t] = acc;
}

__global__ void k_headbn(const float* __restrict__ X, const float* __restrict__ g,
                         const float* __restrict__ b, float* __restrict__ Y, int cols) {
    int t = threadIdx.x;
    if (t >= cols) return;
    float s = 0.f, s2 = 0.f;
    for (int r = 0; r < CELLS; ++r) {
        float v = X[r * cols + t];
        s += v; s2 += v * v;
    }
    float mean = s * (1.0f / CELLS);
    float var = s2 * (1.0f / CELLS) - mean * mean;
    float scale = g[t] * rsqrtf(var + BNEPS);
    float shift = b[t] - mean * scale;
    for (int r = 0; r < CELLS; ++r)
        Y[r * cols + t] = fmaxf(X[r * cols + t] * scale + shift, 0.f);
}

__global__ void k_head2(const float* __restrict__ Y1, const float* __restrict__ W,
                        const float* __restrict__ bias, float* __restrict__ Y2) {
    __shared__ float row[128];
    int c = blockIdx.x, t = threadIdx.x;   // 128 threads
    row[t] = Y1[c * 128 + t];
    __syncthreads();
    if (t < 32) {
        float acc = bias[t];
#pragma unroll 4
        for (int k = 0; k < 128; ++k) acc += row[k] * W[k * 32 + t];
        Y2[c * 32 + t] = acc;
    }
}

// ---------------- launcher ----------------
extern "C" void kernel_launch(void* const* d_in, const int* in_sizes, int n_in,
                              void* d_out, int out_size, void* d_ws, size_t ws_size,
                              hipStream_t stream) {
    const float* x        = (const float*)d_in[0];
    const int*   ei       = (const int*)d_in[1];
    const float* conv1_w  = (const float*)d_in[2];
    const float* conv1_b  = (const float*)d_in[3];
    const float* bn1_g    = (const float*)d_in[4];
    const float* bn1_b    = (const float*)d_in[5];
    const float* conv2_w  = (const float*)d_in[6];
    const float* conv2_b  = (const float*)d_in[7];
    const float* bn2_g    = (const float*)d_in[8];
    const float* bn2_b    = (const float*)d_in[9];
    const float* att_w1   = (const float*)d_in[10];
    const float* att_b1   = (const float*)d_in[11];
    const float* att_w2   = (const float*)d_in[12];
    const float* att_b2   = (const float*)d_in[13];
    const float* fc_w     = (const float*)d_in[14];
    const float* fc_b     = (const float*)d_in[15];
    const float* bne_g    = (const float*)d_in[16];
    const float* bne_b    = (const float*)d_in[17];
    const float* bot_w    = (const float*)d_in[18];
    const float* bot_b    = (const float*)d_in[19];
    const float* bnb_g    = (const float*)d_in[20];
    const float* bnb_b    = (const float*)d_in[21];

    const int* src = ei;
    const int* dst = ei + EE;

    float* y_out   = (float*)d_out;            // [100,32]
    float* emb_out = y_out + CELLS * 32;       // [40000,128]

    float* ws = (float*)d_ws;
    float* bufA   = ws;                        // N*H
    float* bufB   = bufA + (long)NN * HD;      // N*H
    float* dis    = bufB + (long)NN * HD;      // N
    float* scores = dis + NN;                  // N
    float* stats  = scores + NN;               // 256
    float* sstats = stats + 256;               // 256
    float* pooled = sstats + 256;              // C*H
    float* y1pre  = pooled + CELLS * HD;       // C*H
    float* y1     = y1pre + CELLS * HD;        // C*H
    float* y2pre  = y1 + CELLS * HD;           // C*32
    int* ibase    = (int*)(y2pre + CELLS * 32);
    int* deg      = ibase;                     // N
    int* cursor   = deg + NN;                  // N
    int* excl     = cursor + NN;               // N
    int* rowstart = excl + NN;                 // N+1
    int* part     = rowstart + NN + 1;         // NPB
    int* partx    = part + NPB;                // NPB
    int* csr_src  = partx + NPB;               // E

    // ---- CSR build (shared by both convs) ----
    k_zeroi<<<(2 * NN + 255) / 256, 256, 0, stream>>>(deg, 2 * NN);
    k_degcount<<<1024, 256, 0, stream>>>(dst, deg);
    k_scan1<<<NPB, 256, 0, stream>>>(deg, excl, part);
    k_scan2<<<1, 256, 0, stream>>>(part, partx);
    k_scan3<<<NPB, 256, 0, stream>>>(excl, partx, deg, rowstart, dis);
    k_fill<<<2048, 256, 0, stream>>>(src, dst, rowstart, cursor, csr_src);

    // ---- conv1 ----
    k_gemm128<<<625, 256, 0, stream>>>(x, conv1_w, bufA, nullptr);
    k_gather<<<10000, 256, 0, stream>>>(bufA, rowstart, csr_src, dis, conv1_b, bufB);
    k_zero<<<1, 256, 0, stream>>>(stats, 256);
    k_bnstats<<<160, 256, 0, stream>>>(bufB, stats, 250);
    k_bnfinal<<<1, 128, 0, stream>>>(stats, bn1_g, bn1_b, sstats);

    // ---- conv2 (BN1+ReLU fused into GEMM staging) ----
    k_gemm128<<<625, 256, 0, stream>>>(bufB, conv2_w, bufA, sstats);
    k_gather<<<10000, 256, 0, stream>>>(bufA, rowstart, csr_src, dis, conv2_b, bufB);
    k_zero<<<1, 256, 0, stream>>>(stats, 256);
    k_bnstats<<<160, 256, 0, stream>>>(bufB, stats, 250);
    k_bnfinal<<<1, 128, 0, stream>>>(stats, bn2_g, bn2_b, sstats);
    k_bnrelu<<<4096, 256, 0, stream>>>(bufB, sstats, emb_out);

    // ---- attention pooling ----
    k_scores<<<625, 256, 0, stream>>>(emb_out, att_w1, att_b1, att_w2, att_b2, scores);
    k_pool<<<CELLS, 512, 0, stream>>>(emb_out, scores, pooled);

    // ---- head ----
    k_head1<<<CELLS, 128, 0, stream>>>(pooled, fc_w, fc_b, y1pre);
    k_headbn<<<1, 128, 0, stream>>>(y1pre, bne_g, bne_b, y1, 128);
    k_head2<<<CELLS, 128, 0, stream>>>(y1, bot_w, bot_b, y2pre);
    k_headbn<<<1, 64, 0, stream>>>(y2pre, bnb_g, bnb_b, y_out, 32);
}

// Round 4
// 369.393 us; speedup vs baseline: 6.0837x; 1.1744x over previous
//
#include <hip/hip_runtime.h>
#include <math.h>

#define NN   40000
#define EE   640000
#define FD   128
#define HD   128
#define SUBG 400
#define CELLS 100
#define BNEPS 1e-5f
#define NPB  157   // ceil(NN/256)

// ---------------- CSR build ----------------
__global__ void k_zeroi(int* p, int n) {
    int i = blockIdx.x * blockDim.x + threadIdx.x;
    if (i < n) p[i] = 0;
}

__global__ void k_degcount(const int* __restrict__ dst, int* __restrict__ deg) {
    int i = blockIdx.x * blockDim.x + threadIdx.x;
    int stride = gridDim.x * blockDim.x;
    for (; i < EE; i += stride) atomicAdd(&deg[dst[i]], 1);
}

__global__ void k_scan1(const int* __restrict__ deg, int* __restrict__ excl,
                        int* __restrict__ part) {
    __shared__ int s[256];
    int t = threadIdx.x;
    int i = blockIdx.x * 256 + t;
    int v = (i < NN) ? deg[i] : 0;
    s[t] = v;
    __syncthreads();
    for (int off = 1; off < 256; off <<= 1) {
        int add = (t >= off) ? s[t - off] : 0;
        __syncthreads();
        s[t] += add;
        __syncthreads();
    }
    if (i < NN) excl[i] = s[t] - v;
    if (t == 255) part[blockIdx.x] = s[255];
}

__global__ void k_scan2(int* __restrict__ part, int* __restrict__ partx) {
    __shared__ int s[256];
    int t = threadIdx.x;
    int v = (t < NPB) ? part[t] : 0;
    s[t] = v;
    __syncthreads();
    for (int off = 1; off < 256; off <<= 1) {
        int add = (t >= off) ? s[t - off] : 0;
        __syncthreads();
        s[t] += add;
        __syncthreads();
    }
    if (t < NPB) partx[t] = s[t] - v;
}

__global__ void k_scan3(const int* __restrict__ excl, const int* __restrict__ partx,
                        const int* __restrict__ deg, int* __restrict__ rowstart,
                        float* __restrict__ dis) {
    int i = blockIdx.x * 256 + threadIdx.x;
    if (i < NN) {
        rowstart[i] = excl[i] + partx[blockIdx.x];
        dis[i] = rsqrtf((float)(deg[i] + 1));   // +1 self-loop
    }
    if (i == 0) rowstart[NN] = EE;
}

__global__ void k_fill(const int* __restrict__ src, const int* __restrict__ dst,
                       const int* __restrict__ rowstart, int* __restrict__ cursor,
                       int* __restrict__ csr_src) {
    int i = blockIdx.x * blockDim.x + threadIdx.x;
    int stride = gridDim.x * blockDim.x;
    for (; i < EE; i += stride) {
        int d = dst[i];
        int slot = rowstart[d] + atomicAdd(&cursor[d], 1);
        csr_src[slot] = src[i];
    }
}

// ---------------- tiled GEMM  Y[M,128] = X[M,128] @ W[128,128] ----------------
// 64-row LDS tile as float4[64][32] linear. Thread = 8 rows x 4 cols:
// float4 acc[8] statically indexed (no spill). Reads from LDS are
// wave-uniform per instruction (broadcast, conflict-free).
// Optional fused input BN+ReLU during staging (ss != nullptr).
__global__ __launch_bounds__(256, 2)
void k_gemm128(const float* __restrict__ X, const float* __restrict__ W,
               float* __restrict__ Y, const float* __restrict__ ss) {
    __shared__ float4 xs[64 * 32];   // 32 KB
    int t = threadIdx.x;
    long rowbase = (long)blockIdx.x * 64;
    const float4* Xv = (const float4*)(X + rowbase * 128);
    if (ss) {
#pragma unroll
        for (int i = 0; i < 8; ++i) {
            int f = t + 256 * i;
            int c4 = (f & 31) * 4;
            float4 v = Xv[f];
            float4 sc = *(const float4*)&ss[c4];
            float4 sh = *(const float4*)&ss[128 + c4];
            v.x = fmaxf(fmaf(v.x, sc.x, sh.x), 0.f);
            v.y = fmaxf(fmaf(v.y, sc.y, sh.y), 0.f);
            v.z = fmaxf(fmaf(v.z, sc.z, sh.z), 0.f);
            v.w = fmaxf(fmaf(v.w, sc.w, sh.w), 0.f);
            xs[f] = v;
        }
    } else {
#pragma unroll
        for (int i = 0; i < 8; ++i)
            xs[t + 256 * i] = Xv[t + 256 * i];
    }
    __syncthreads();

    int cg = t & 31;            // col group: cols cg*4 .. cg*4+3
    int r0 = (t >> 5) * 8;      // 8 rows
    const float4* Wv = (const float4*)W;   // W[k][c]: k*32 + cg

    float4 acc[8];
#pragma unroll
    for (int i = 0; i < 8; ++i) acc[i] = make_float4(0.f, 0.f, 0.f, 0.f);

    for (int k4 = 0; k4 < 32; ++k4) {
        float4 w0 = Wv[(4 * k4 + 0) * 32 + cg];
        float4 w1 = Wv[(4 * k4 + 1) * 32 + cg];
        float4 w2 = Wv[(4 * k4 + 2) * 32 + cg];
        float4 w3 = Wv[(4 * k4 + 3) * 32 + cg];
#pragma unroll
        for (int i = 0; i < 8; ++i) {
            float4 xv = xs[(r0 + i) * 32 + k4];
            acc[i].x = fmaf(xv.x, w0.x, acc[i].x);
            acc[i].x = fmaf(xv.y, w1.x, acc[i].x);
            acc[i].x = fmaf(xv.z, w2.x, acc[i].x);
            acc[i].x = fmaf(xv.w, w3.x, acc[i].x);
            acc[i].y = fmaf(xv.x, w0.y, acc[i].y);
            acc[i].y = fmaf(xv.y, w1.y, acc[i].y);
            acc[i].y = fmaf(xv.z, w2.y, acc[i].y);
            acc[i].y = fmaf(xv.w, w3.y, acc[i].y);
            acc[i].z = fmaf(xv.x, w0.z, acc[i].z);
            acc[i].z = fmaf(xv.y, w1.z, acc[i].z);
            acc[i].z = fmaf(xv.z, w2.z, acc[i].z);
            acc[i].z = fmaf(xv.w, w3.z, acc[i].z);
            acc[i].w = fmaf(xv.x, w0.w, acc[i].w);
            acc[i].w = fmaf(xv.y, w1.w, acc[i].w);
            acc[i].w = fmaf(xv.z, w2.w, acc[i].w);
            acc[i].w = fmaf(xv.w, w3.w, acc[i].w);
        }
    }
    float4* yout = (float4*)(Y + (rowbase + r0) * 128) + cg;
#pragma unroll
    for (int i = 0; i < 8; ++i)
        yout[i * 32] = acc[i];
}

// ---------------- GCN aggregation: CSR gather, fused self-loop + bias ----------------
__global__ void k_gather(const float* __restrict__ Hm, const int* __restrict__ rowstart,
                         const int* __restrict__ csr_src, const float* __restrict__ dis,
                         const float* __restrict__ bias, float* __restrict__ out) {
    int lane = threadIdx.x & 63;
    int node = (blockIdx.x * blockDim.x + threadIdx.x) >> 6;
    if (node >= NN) return;
    float dd = dis[node];
    float2 h0 = *(const float2*)&Hm[(long)node * 128 + 2 * lane];
    float2 acc = { h0.x * dd, h0.y * dd };
    int e  = rowstart[node];
    int e1 = rowstart[node + 1];
    for (; e + 3 < e1; e += 4) {
        int s0 = csr_src[e], s1 = csr_src[e + 1], s2 = csr_src[e + 2], s3 = csr_src[e + 3];
        float d0 = dis[s0], d1 = dis[s1], d2 = dis[s2], d3 = dis[s3];
        float2 v0 = *(const float2*)&Hm[(long)s0 * 128 + 2 * lane];
        float2 v1 = *(const float2*)&Hm[(long)s1 * 128 + 2 * lane];
        float2 v2 = *(const float2*)&Hm[(long)s2 * 128 + 2 * lane];
        float2 v3 = *(const float2*)&Hm[(long)s3 * 128 + 2 * lane];
        acc.x += v0.x * d0; acc.y += v0.y * d0;
        acc.x += v1.x * d1; acc.y += v1.y * d1;
        acc.x += v2.x * d2; acc.y += v2.y * d2;
        acc.x += v3.x * d3; acc.y += v3.y * d3;
    }
    for (; e < e1; ++e) {
        int s0 = csr_src[e];
        float d0 = dis[s0];
        float2 v0 = *(const float2*)&Hm[(long)s0 * 128 + 2 * lane];
        acc.x += v0.x * d0; acc.y += v0.y * d0;
    }
    float2 b2 = *(const float2*)&bias[2 * lane];
    float2 o = { acc.x * dd + b2.x, acc.y * dd + b2.y };
    *(float2*)&out[(long)node * 128 + 2 * lane] = o;
}

// ---------------- BatchNorm ----------------
__global__ void k_zero(float* p, int n) {
    int i = blockIdx.x * blockDim.x + threadIdx.x;
    if (i < n) p[i] = 0.f;
}

__global__ void k_bnstats(const float* __restrict__ X, float* __restrict__ stats,
                          int rowsPerBlock) {
    __shared__ float ls[256], ls2[256];
    int t = threadIdx.x;
    int col = t & 127, half = t >> 7;
    int r0 = blockIdx.x * rowsPerBlock;
    int r1 = r0 + rowsPerBlock; if (r1 > NN) r1 = NN;
    float s = 0.f, s2 = 0.f;
    for (int r = r0 + half; r < r1; r += 2) {
        float v = X[(long)r * 128 + col];
        s += v; s2 += v * v;
    }
    ls[t] = s; ls2[t] = s2;
    __syncthreads();
    if (t < 128) {
        s  = ls[t]  + ls[t + 128];
        s2 = ls2[t] + ls2[t + 128];
        atomicAdd(&stats[col], s);
        atomicAdd(&stats[128 + col], s2);
    }
}

__global__ void k_bnfinal(const float* __restrict__ stats, const float* __restrict__ g,
                          const float* __restrict__ b, float* __restrict__ ss) {
    int c = threadIdx.x;
    if (c < 128) {
        float mean = stats[c] * (1.0f / NN);
        float var  = stats[128 + c] * (1.0f / NN) - mean * mean;
        float scale = g[c] * rsqrtf(var + BNEPS);
        ss[c] = scale;
        ss[128 + c] = b[c] - mean * scale;
    }
}

__global__ void k_bnrelu(const float* __restrict__ X, const float* __restrict__ ss,
                         float* __restrict__ Y) {
    int i = blockIdx.x * blockDim.x + threadIdx.x;
    int total = NN * HD / 4;
    int stride = gridDim.x * blockDim.x;
    for (; i < total; i += stride) {
        int c4 = (i & 31) * 4;
        float4 v = ((const float4*)X)[i];
        float4 sc = *(const float4*)&ss[c4];
        float4 sh = *(const float4*)&ss[128 + c4];
        float4 o;
        o.x = fmaxf(v.x * sc.x + sh.x, 0.f);
        o.y = fmaxf(v.y * sc.y + sh.y, 0.f);
        o.z = fmaxf(v.z * sc.z + sh.z, 0.f);
        o.w = fmaxf(v.w * sc.w + sh.w, 0.f);
        ((float4*)Y)[i] = o;
    }
}

// ---------------- attention scores (tiled): tanh(x@W1+b1)@w2 + b2 ----------------
// Same tile scheme: 64 rows/block, thread = 4 rows x 4 cols of the 64-wide
// intermediate; tanh + w2-dot + 16-lane shfl reduce epilogue.
__global__ __launch_bounds__(256, 2)
void k_scores(const float* __restrict__ emb, const float* __restrict__ w1,
              const float* __restrict__ b1, const float* __restrict__ w2,
              const float* __restrict__ b2, float* __restrict__ scores) {
    __shared__ float4 xs[64 * 32];  // 32 KB
    int t = threadIdx.x;
    long rowbase = (long)blockIdx.x * 64;
    const float4* Xv = (const float4*)(emb + rowbase * 128);
#pragma unroll
    for (int i = 0; i < 8; ++i)
        xs[t + 256 * i] = Xv[t + 256 * i];
    __syncthreads();

    int cg = t & 15;            // col group: cols cg*4 .. +3 (of 64)
    int r0 = (t >> 4) * 4;      // 4 rows
    const float4* Wv = (const float4*)w1;   // w1[k][c]: k*16 + cg
    float4 bb = ((const float4*)b1)[cg];

    float4 acc[4];
#pragma unroll
    for (int i = 0; i < 4; ++i) acc[i] = bb;

    for (int k4 = 0; k4 < 32; ++k4) {
        float4 w0 = Wv[(4 * k4 + 0) * 16 + cg];
        float4 w1v = Wv[(4 * k4 + 1) * 16 + cg];
        float4 w2v = Wv[(4 * k4 + 2) * 16 + cg];
        float4 w3 = Wv[(4 * k4 + 3) * 16 + cg];
#pragma unroll
        for (int i = 0; i < 4; ++i) {
            float4 xv = xs[(r0 + i) * 32 + k4];
            acc[i].x = fmaf(xv.x, w0.x, acc[i].x);
            acc[i].x = fmaf(xv.y, w1v.x, acc[i].x);
            acc[i].x = fmaf(xv.z, w2v.x, acc[i].x);
            acc[i].x = fmaf(xv.w, w3.x, acc[i].x);
            acc[i].y = fmaf(xv.x, w0.y, acc[i].y);
            acc[i].y = fmaf(xv.y, w1v.y, acc[i].y);
            acc[i].y = fmaf(xv.z, w2v.y, acc[i].y);
            acc[i].y = fmaf(xv.w, w3.y, acc[i].y);
            acc[i].z = fmaf(xv.x, w0.z, acc[i].z);
            acc[i].z = fmaf(xv.y, w1v.z, acc[i].z);
            acc[i].z = fmaf(xv.z, w2v.z, acc[i].z);
            acc[i].z = fmaf(xv.w, w3.z, acc[i].z);
            acc[i].w = fmaf(xv.x, w0.w, acc[i].w);
            acc[i].w = fmaf(xv.y, w1v.w, acc[i].w);
            acc[i].w = fmaf(xv.z, w2v.w, acc[i].w);
            acc[i].w = fmaf(xv.w, w3.w, acc[i].w);
        }
    }
    float4 w2v = ((const float4*)w2)[cg];
    float b2v = b2[0];
#pragma unroll
    for (int i = 0; i < 4; ++i) {
        float v = tanhf(acc[i].x) * w2v.x + tanhf(acc[i].y) * w2v.y
                + tanhf(acc[i].z) * w2v.z + tanhf(acc[i].w) * w2v.w;
        v += __shfl_xor(v, 1);
        v += __shfl_xor(v, 2);
        v += __shfl_xor(v, 4);
        v += __shfl_xor(v, 8);
        if (cg == 0) scores[rowbase + r0 + i] = v + b2v;
    }
}

// ---------------- softmax over genes within cell + weighted pool ----------------
__global__ void k_pool(const float* __restrict__ emb, const float* __restrict__ scores,
                       float* __restrict__ pooled) {
    __shared__ float sl[SUBG];
    __shared__ float red[512];
    int c = blockIdx.x;
    int t = threadIdx.x;   // 512 threads
    int base = c * SUBG;
    float lmax = -1e30f;
    for (int i = t; i < SUBG; i += 512) {
        float v = scores[base + i];
        sl[i] = v;
        lmax = fmaxf(lmax, v);
    }
    red[t] = lmax; __syncthreads();
    for (int off = 256; off > 0; off >>= 1) {
        if (t < off) red[t] = fmaxf(red[t], red[t + off]);
        __syncthreads();
    }
    float mx = red[0]; __syncthreads();
    float lsum = 0.f;
    for (int i = t; i < SUBG; i += 512) {
        float e = __expf(sl[i] - mx);
        sl[i] = e;
        lsum += e;
    }
    red[t] = lsum; __syncthreads();
    for (int off = 256; off > 0; off >>= 1) {
        if (t < off) red[t] += red[t + off];
        __syncthreads();
    }
    float inv = 1.0f / red[0];
    __syncthreads();
    int col = t & 127, grp = t >> 7;   // 4 row-groups
    float acc = 0.f;
#pragma unroll 2
    for (int s = grp; s < SUBG; s += 4)
        acc += sl[s] * emb[(long)(base + s) * 128 + col];
    red[t] = acc; __syncthreads();
    if (grp == 0)
        pooled[c * 128 + col] = (red[col] + red[128 + col] + red[256 + col] + red[384 + col]) * inv;
}

// ---------------- dense head ----------------
__global__ void k_head1(const float* __restrict__ pooled, const float* __restrict__ W,
                        const float* __restrict__ bias, float* __restrict__ Y) {
    __shared__ float row[128];
    int c = blockIdx.x, t = threadIdx.x;
    row[t] = pooled[c * 128 + t];
    __syncthreads();
    float acc = bias[t];
#pragma unroll 4
    for (int k = 0; k < 128; ++k) acc += row[k] * W[k * 128 + t];
    Y[c * 128 + t] = acc;
}

__global__ void k_headbn(const float* __restrict__ X, const float* __restrict__ g,
                         const float* __restrict__ b, float* __restrict__ Y, int cols) {
    int t = threadIdx.x;
    if (t >= cols) return;
    float s = 0.f, s2 = 0.f;
    for (int r = 0; r < CELLS; ++r) {
        float v = X[r * cols + t];
        s += v; s2 += v * v;
    }
    float mean = s * (1.0f / CELLS);
    float var = s2 * (1.0f / CELLS) - mean * mean;
    float scale = g[t] * rsqrtf(var + BNEPS);
    float shift = b[t] - mean * scale;
    for (int r = 0; r < CELLS; ++r)
        Y[r * cols + t] = fmaxf(X[r * cols + t] * scale + shift, 0.f);
}

__global__ void k_head2(const float* __restrict__ Y1, const float* __restrict__ W,
                        const float* __restrict__ bias, float* __restrict__ Y2) {
    __shared__ float row[128];
    int c = blockIdx.x, t = threadIdx.x;   // 128 threads
    row[t] = Y1[c * 128 + t];
    __syncthreads();
    if (t < 32) {
        float acc = bias[t];
#pragma unroll 4
        for (int k = 0; k < 128; ++k) acc += row[k] * W[k * 32 + t];
        Y2[c * 32 + t] = acc;
    }
}

// ---------------- launcher ----------------
extern "C" void kernel_launch(void* const* d_in, const int* in_sizes, int n_in,
                              void* d_out, int out_size, void* d_ws, size_t ws_size,
                              hipStream_t stream) {
    const float* x        = (const float*)d_in[0];
    const int*   ei       = (const int*)d_in[1];
    const float* conv1_w  = (const float*)d_in[2];
    const float* conv1_b  = (const float*)d_in[3];
    const float* bn1_g    = (const float*)d_in[4];
    const float* bn1_b    = (const float*)d_in[5];
    const float* conv2_w  = (const float*)d_in[6];
    const float* conv2_b  = (const float*)d_in[7];
    const float* bn2_g    = (const float*)d_in[8];
    const float* bn2_b    = (const float*)d_in[9];
    const float* att_w1   = (const float*)d_in[10];
    const float* att_b1   = (const float*)d_in[11];
    const float* att_w2   = (const float*)d_in[12];
    const float* att_b2   = (const float*)d_in[13];
    const float* fc_w     = (const float*)d_in[14];
    const float* fc_b     = (const float*)d_in[15];
    const float* bne_g    = (const float*)d_in[16];
    const float* bne_b    = (const float*)d_in[17];
    const float* bot_w    = (const float*)d_in[18];
    const float* bot_b    = (const float*)d_in[19];
    const float* bnb_g    = (const float*)d_in[20];
    const float* bnb_b    = (const float*)d_in[21];

    const int* src = ei;
    const int* dst = ei + EE;

    float* y_out   = (float*)d_out;            // [100,32]
    float* emb_out = y_out + CELLS * 32;       // [40000,128]

    float* ws = (float*)d_ws;
    float* bufA   = ws;                        // N*H
    float* bufB   = bufA + (long)NN * HD;      // N*H
    float* dis    = bufB + (long)NN * HD;      // N
    float* scores = dis + NN;                  // N
    float* stats  = scores + NN;               // 256
    float* sstats = stats + 256;               // 256
    float* pooled = sstats + 256;              // C*H
    float* y1pre  = pooled + CELLS * HD;       // C*H
    float* y1     = y1pre + CELLS * HD;        // C*H
    float* y2pre  = y1 + CELLS * HD;           // C*32
    int* ibase    = (int*)(y2pre + CELLS * 32);
    int* deg      = ibase;                     // N
    int* cursor   = deg + NN;                  // N
    int* excl     = cursor + NN;               // N
    int* rowstart = excl + NN;                 // N+1
    int* part     = rowstart + NN + 1;         // NPB
    int* partx    = part + NPB;                // NPB
    int* csr_src  = partx + NPB;               // E

    // ---- CSR build (shared by both convs) ----
    k_zeroi<<<(2 * NN + 255) / 256, 256, 0, stream>>>(deg, 2 * NN);
    k_degcount<<<1024, 256, 0, stream>>>(dst, deg);
    k_scan1<<<NPB, 256, 0, stream>>>(deg, excl, part);
    k_scan2<<<1, 256, 0, stream>>>(part, partx);
    k_scan3<<<NPB, 256, 0, stream>>>(excl, partx, deg, rowstart, dis);
    k_fill<<<2048, 256, 0, stream>>>(src, dst, rowstart, cursor, csr_src);

    // ---- conv1 ----
    k_gemm128<<<625, 256, 0, stream>>>(x, conv1_w, bufA, nullptr);
    k_gather<<<10000, 256, 0, stream>>>(bufA, rowstart, csr_src, dis, conv1_b, bufB);
    k_zero<<<1, 256, 0, stream>>>(stats, 256);
    k_bnstats<<<160, 256, 0, stream>>>(bufB, stats, 250);
    k_bnfinal<<<1, 128, 0, stream>>>(stats, bn1_g, bn1_b, sstats);

    // ---- conv2 (BN1+ReLU fused into GEMM staging) ----
    k_gemm128<<<625, 256, 0, stream>>>(bufB, conv2_w, bufA, sstats);
    k_gather<<<10000, 256, 0, stream>>>(bufA, rowstart, csr_src, dis, conv2_b, bufB);
    k_zero<<<1, 256, 0, stream>>>(stats, 256);
    k_bnstats<<<160, 256, 0, stream>>>(bufB, stats, 250);
    k_bnfinal<<<1, 128, 0, stream>>>(stats, bn2_g, bn2_b, sstats);
    k_bnrelu<<<4096, 256, 0, stream>>>(bufB, sstats, emb_out);

    // ---- attention pooling ----
    k_scores<<<625, 256, 0, stream>>>(emb_out, att_w1, att_b1, att_w2, att_b2, scores);
    k_pool<<<CELLS, 512, 0, stream>>>(emb_out, scores, pooled);

    // ---- head ----
    k_head1<<<CELLS, 128, 0, stream>>>(pooled, fc_w, fc_b, y1pre);
    k_headbn<<<1, 128, 0, stream>>>(y1pre, bne_g, bne_b, y1, 128);
    k_head2<<<CELLS, 128, 0, stream>>>(y1, bot_w, bot_b, y2pre);
    k_headbn<<<1, 64, 0, stream>>>(y2pre, bnb_g, bnb_b, y_out, 32);
}